// Round 1
// baseline (809.885 us; speedup 1.0000x reference)
//
#include <hip/hip_runtime.h>
#include <hip/hip_bf16.h>

// Geo2Vec fused MLP, bf16 MFMA version.
// Inputs: 0 xy(B,2) f32, 1 idx(B) i32, 2 emb(100000,256) f32, 3 W1a(320,256),
// 4 b1a(256), 5 W1b(256,256), 6 b1b(256), 7 Wa(8,576,256), 8 ba(8,256),
// 9 Wb(8,256,256), 10 bb(8,256), 11 W2(256,1), 12 b2(1). Out: (B,1) f32.

typedef __attribute__((ext_vector_type(8))) __bf16 bfv8;
typedef __attribute__((ext_vector_type(4))) float f32x4;
typedef __attribute__((ext_vector_type(4))) int i32x4;

__device__ __forceinline__ short f2bf(float f) {
  unsigned u = __builtin_bit_cast(unsigned, f);
  u = (u + 0x7fffu + ((u >> 16) & 1u)) >> 16;
  return (short)u;
}
__device__ __forceinline__ float bf2f(short s) {
  unsigned u = ((unsigned)(unsigned short)s) << 16;
  return __builtin_bit_cast(float, u);
}
// XOR-swizzled LDS byte address (bank-conflict fix for 128-multiple strides)
__device__ __forceinline__ int swzaddr(int base, int stride, int row, int colbyte) {
  return base + row * stride + (colbyte ^ ((row & 7) << 4));
}

// ---------------- weight pack: fp32 row-major (K,256) -> bf16 B-frag-major ----
// packet p = (kt*16 + nt)*64 + lane ; dst[p*8+i] = W[kt*32 + 8*(lane>>4) + i][nt*16 + (lane&15)]
__global__ void pack_weights_kernel(const float* __restrict__ W1a, const float* __restrict__ W1b,
                                    const float* __restrict__ Wa, const float* __restrict__ Wb,
                                    short* __restrict__ ws) {
  int p = blockIdx.x * blockDim.x + threadIdx.x;
  const int P1 = 10240;           // W1a: 10 kt * 16 nt * 64
  const int P2 = P1 + 8192;       // W1b: 8*16*64
  const int P3 = P2 + 8 * 18432;  // Wa: 8 layers * 18*16*64
  const int P4 = P3 + 8 * 8192;   // Wb
  if (p >= P4) return;
  const float* src;
  int q;
  if (p < P1)      { src = W1a; q = p; }
  else if (p < P2) { src = W1b; q = p - P1; }
  else if (p < P3) { q = p - P2; int l = q / 18432; q -= l * 18432; src = Wa + l * 147456; }
  else             { q = p - P3; int l = q / 8192;  q -= l * 8192;  src = Wb + l * 65536; }
  const int lane = q & 63, t = q >> 6, nt = t & 15, kt = t >> 4;
  const int k0 = kt * 32 + ((lane >> 4) << 3);
  const int n  = (nt << 4) + (lane & 15);
  short* dst = ws + (size_t)p * 8;
#pragma unroll
  for (int i = 0; i < 8; ++i) dst[i] = f2bf(src[(size_t)(k0 + i) * 256 + n]);
}

// ---------------- fused MLP ----------------
// LDS layout (bytes): xyz [0, 40960) stride 640 ; x [40960, 73728) stride 512 ;
//                     t [73728, 106496) stride 512
__device__ __forceinline__ void do_gemm(short* lds,
    int a1Base, int a1Stride, int a2Base, int a2Stride, int splitKt, int nkt,
    const short* __restrict__ wp, const float* __restrict__ bias, bool leaky,
    int outBase, int outStride, int wave, int lane)
{
  f32x4 acc[4][2];
#pragma unroll
  for (int i = 0; i < 4; ++i) { acc[i][0] = (f32x4)0.f; acc[i][1] = (f32x4)0.f; }
  const int nt0 = wave << 1;  // this wave owns n-tiles nt0, nt0+1 (cols 32*wave..+32)
  for (int kt = 0; kt < nkt; ++kt) {
    const bfv8 b0 = *(const bfv8*)(wp + (((size_t)(kt * 16 + nt0)     * 64 + lane) << 3));
    const bfv8 b1 = *(const bfv8*)(wp + (((size_t)(kt * 16 + nt0 + 1) * 64 + lane) << 3));
    const bool first = (kt < splitKt);
    const int base   = first ? a1Base : a2Base;
    const int stride = first ? a1Stride : a2Stride;
    const int kbyte  = (first ? kt : kt - splitKt) * 64 + ((lane >> 4) << 4);
#pragma unroll
    for (int rt = 0; rt < 4; ++rt) {
      const int arow = (rt << 4) + (lane & 15);
      const bfv8 a = *(const bfv8*)((const char*)lds + swzaddr(base, stride, arow, kbyte));
      acc[rt][0] = __builtin_amdgcn_mfma_f32_16x16x32_bf16(a, b0, acc[rt][0], 0, 0, 0);
      acc[rt][1] = __builtin_amdgcn_mfma_f32_16x16x32_bf16(a, b1, acc[rt][1], 0, 0, 0);
    }
  }
#pragma unroll
  for (int rt = 0; rt < 4; ++rt)
#pragma unroll
    for (int ct = 0; ct < 2; ++ct) {
      const int col = ((nt0 + ct) << 4) + (lane & 15);
      const float bv = bias[col];
#pragma unroll
      for (int rr = 0; rr < 4; ++rr) {
        const int orow = (rt << 4) + ((lane >> 4) << 2) + rr;
        float v = acc[rt][ct][rr] + bv;
        if (leaky) v = (v >= 0.f) ? v : 0.01f * v;
        *(short*)((char*)lds + swzaddr(outBase, outStride, orow, col << 1)) = f2bf(v);
      }
    }
}

__launch_bounds__(512, 1)
__global__ void geo2vec_kernel(const float* __restrict__ xy, const int* __restrict__ idx,
    const float* __restrict__ emb,
    const float* __restrict__ b1a, const float* __restrict__ b1b,
    const float* __restrict__ ba, const float* __restrict__ bb,
    const float* __restrict__ W2, const float* __restrict__ b2,
    const short* __restrict__ wp, float* __restrict__ out)
{
  __shared__ short lds[53248];  // 104 KB
  const int tid = threadIdx.x;

  // ---- prologue: pos-encode + gather z -> xyz tile (64 x 320 bf16) ----
  {
    const int g = tid >> 3, j = tid & 7;  // 8 threads per row
    const int row = blockIdx.x * 64 + g;
    const float xv = xy[2 * row], yv = xy[2 * row + 1];
    const float rv = sqrtf(xv * xv + yv * yv);
    union { short s[8]; i32x4 v; } tmp;
#pragma unroll
    for (int i = 0; i < 8; ++i) {
      const int c = 8 * j + i;
      float fv;
      if (c < 2)       fv = c ? yv : xv;
      else if (c < 22) { int m = c - 2;  float f = 1.0f + (5.0f / 9.0f) * (m >> 1); fv = sinf(((m & 1) ? yv : xv) * f); }
      else if (c < 42) { int m = c - 22; float f = 1.0f + (5.0f / 9.0f) * (m >> 1); fv = cosf(((m & 1) ? yv : xv) * f); }
      else if (c < 44) fv = (c == 42) ? xv : yv;
      else if (c < 54) fv = sinf(rv * (1.0f + (5.0f / 9.0f) * (c - 44)));
      else             fv = cosf(rv * (1.0f + (5.0f / 9.0f) * (c - 54)));
      tmp.s[i] = f2bf(fv);
    }
    *(i32x4*)((char*)lds + swzaddr(0, 640, g, j << 4)) = tmp.v;
    const float* zr = emb + (size_t)(unsigned)idx[row] * 256;
#pragma unroll
    for (int c4 = 0; c4 < 4; ++c4) {
      const int cel = j * 32 + c4 * 8;  // z element 0..255
      const float4 f0 = *(const float4*)(zr + cel);
      const float4 f1 = *(const float4*)(zr + cel + 4);
      union { short s[8]; i32x4 v; } t2;
      t2.s[0] = f2bf(f0.x); t2.s[1] = f2bf(f0.y); t2.s[2] = f2bf(f0.z); t2.s[3] = f2bf(f0.w);
      t2.s[4] = f2bf(f1.x); t2.s[5] = f2bf(f1.y); t2.s[6] = f2bf(f1.z); t2.s[7] = f2bf(f1.w);
      *(i32x4*)((char*)lds + swzaddr(0, 640, g, (64 + cel) << 1)) = t2.v;
    }
  }
  __syncthreads();

  const int wave = tid >> 6, lane = tid & 63;
  // layer 1: t = leaky(xyz @ W1a + b1a) ; x = t @ W1b + b1b
  do_gemm(lds, 0, 640, 0, 640, 10, 10, wp, b1a, true, 73728, 512, wave, lane);
  __syncthreads();
  do_gemm(lds, 73728, 512, 73728, 512, 8, 8, wp + 81920, b1b, false, 40960, 512, wave, lane);
  __syncthreads();
  // 8 mid layers: t = leaky([xyz|x] @ Wa + ba) ; x = t @ Wb + bb
  for (int l = 0; l < 8; ++l) {
    do_gemm(lds, 0, 640, 40960, 512, 10, 18, wp + 147456 + l * 147456, ba + l * 256, true, 73728, 512, wave, lane);
    __syncthreads();
    do_gemm(lds, 73728, 512, 73728, 512, 8, 8, wp + 1327104 + l * 65536, bb + l * 256, false, 40960, 512, wave, lane);
    __syncthreads();
  }
  // final: out = x @ W2 + b2
  if (tid < 64) {
    float s = 0.f;
#pragma unroll
    for (int c = 0; c < 32; ++c) {
      const short* v = (const short*)((const char*)lds + swzaddr(40960, 512, tid, c << 4));
#pragma unroll
      for (int jj = 0; jj < 8; ++jj) s += bf2f(v[jj]) * W2[(c << 3) + jj];
    }
    out[blockIdx.x * 64 + tid] = s + b2[0];
  }
}

extern "C" void kernel_launch(void* const* d_in, const int* in_sizes, int n_in,
                              void* d_out, int out_size, void* d_ws, size_t ws_size,
                              hipStream_t stream) {
  const float* xy  = (const float*)d_in[0];
  const int*   idx = (const int*)d_in[1];
  const float* emb = (const float*)d_in[2];
  const float* W1a = (const float*)d_in[3];
  const float* b1a = (const float*)d_in[4];
  const float* W1b = (const float*)d_in[5];
  const float* b1b = (const float*)d_in[6];
  const float* Wa  = (const float*)d_in[7];
  const float* ba  = (const float*)d_in[8];
  const float* Wb  = (const float*)d_in[9];
  const float* bb  = (const float*)d_in[10];
  const float* W2  = (const float*)d_in[11];
  const float* b2  = (const float*)d_in[12];
  short* ws = (short*)d_ws;  // 3,702,784 B of packed bf16 weights
  const int B = in_sizes[1];

  // 231424 packets total / 256
  hipLaunchKernelGGL(pack_weights_kernel, dim3(904), dim3(256), 0, stream,
                     W1a, W1b, Wa, Wb, ws);
  hipLaunchKernelGGL(geo2vec_kernel, dim3(B / 64), dim3(512), 0, stream,
                     xy, idx, emb, b1a, b1b, ba, bb, W2, b2, ws, (float*)d_out);
}

// Round 3
// 809.322 us; speedup vs baseline: 1.0007x; 1.0007x over previous
//
#include <hip/hip_runtime.h>
#include <hip/hip_bf16.h>

// Geo2Vec fused MLP, bf16 MFMA version. Round 3: round-2's fully-unrolled
// templated GEMMs, but back to __launch_bounds__(512,1) — the (512,2) bound
// forced VGPR<=128 -> spills; LDS (104KB) caps us at 1 block/CU anyway so
// VGPRs up to 256 are free.

typedef __attribute__((ext_vector_type(8))) __bf16 bfv8;
typedef __attribute__((ext_vector_type(4))) float f32x4;
typedef __attribute__((ext_vector_type(4))) int i32x4;

__device__ __forceinline__ short f2bf(float f) {
  unsigned u = __builtin_bit_cast(unsigned, f);
  u = (u + 0x7fffu + ((u >> 16) & 1u)) >> 16;
  return (short)u;
}
__device__ __forceinline__ float bf2f(short s) {
  unsigned u = ((unsigned)(unsigned short)s) << 16;
  return __builtin_bit_cast(float, u);
}
// XOR-swizzled LDS byte address (bank-conflict fix for 128-multiple strides)
__device__ __forceinline__ int swzaddr(int base, int stride, int row, int colbyte) {
  return base + row * stride + (colbyte ^ ((row & 7) << 4));
}

// ---------------- weight pack: fp32 row-major (K,256) -> bf16 B-frag-major ----
// packet p = (kt*16 + nt)*64 + lane ; dst[p*8+i] = W[kt*32 + 8*(lane>>4) + i][nt*16 + (lane&15)]
__global__ void pack_weights_kernel(const float* __restrict__ W1a, const float* __restrict__ W1b,
                                    const float* __restrict__ Wa, const float* __restrict__ Wb,
                                    short* __restrict__ ws) {
  int p = blockIdx.x * blockDim.x + threadIdx.x;
  const int P1 = 10240;           // W1a: 10 kt * 16 nt * 64
  const int P2 = P1 + 8192;       // W1b: 8*16*64
  const int P3 = P2 + 8 * 18432;  // Wa: 8 layers * 18*16*64
  const int P4 = P3 + 8 * 8192;   // Wb
  if (p >= P4) return;
  const float* src;
  int q;
  if (p < P1)      { src = W1a; q = p; }
  else if (p < P2) { src = W1b; q = p - P1; }
  else if (p < P3) { q = p - P2; int l = q / 18432; q -= l * 18432; src = Wa + l * 147456; }
  else             { q = p - P3; int l = q / 8192;  q -= l * 8192;  src = Wb + l * 65536; }
  const int lane = q & 63, t = q >> 6, nt = t & 15, kt = t >> 4;
  const int k0 = kt * 32 + ((lane >> 4) << 3);
  const int n  = (nt << 4) + (lane & 15);
  short* dst = ws + (size_t)p * 8;
#pragma unroll
  for (int i = 0; i < 8; ++i) dst[i] = f2bf(src[(size_t)(k0 + i) * 256 + n]);
}

// ---------------- fused MLP ----------------
// LDS layout (bytes): xyz [0, 40960) stride 640 ; x [40960, 73728) stride 512 ;
//                     t [73728, 106496) stride 512
template<int NKT, int SPLITKT, bool LEAKY>
__device__ __forceinline__ void do_gemm(short* lds,
    int a1Base, int a1Stride, int a2Base, int a2Stride,
    const short* __restrict__ wp, const float* __restrict__ bias,
    int outBase, int wave, int lane)
{
  const int lo = lane & 15, hi = lane >> 4;
  const int nt0 = wave << 1;  // this wave owns cols 32*wave .. +32
  const float bv0 = bias[(nt0 << 4) + lo];        // hoisted: latency hides under kt loop
  const float bv1 = bias[(nt0 << 4) + 16 + lo];
  f32x4 acc[4][2];
#pragma unroll
  for (int i = 0; i < 4; ++i) { acc[i][0] = (f32x4)0.f; acc[i][1] = (f32x4)0.f; }
  const short* wbase = wp + (((size_t)nt0 * 64 + lane) << 3);
#pragma unroll
  for (int kt = 0; kt < NKT; ++kt) {
    const bfv8 b0 = *(const bfv8*)(wbase + (size_t)kt * 8192);
    const bfv8 b1 = *(const bfv8*)(wbase + (size_t)kt * 8192 + 512);
    const int base   = (kt < SPLITKT) ? a1Base : a2Base;
    const int stride = (kt < SPLITKT) ? a1Stride : a2Stride;
    const int kk     = (kt < SPLITKT) ? kt : kt - SPLITKT;
    const int kbyte  = kk * 64 + (hi << 4);
#pragma unroll
    for (int rt = 0; rt < 4; ++rt) {
      const bfv8 a = *(const bfv8*)((const char*)lds + swzaddr(base, stride, (rt << 4) + lo, kbyte));
      acc[rt][0] = __builtin_amdgcn_mfma_f32_16x16x32_bf16(a, b0, acc[rt][0], 0, 0, 0);
      acc[rt][1] = __builtin_amdgcn_mfma_f32_16x16x32_bf16(a, b1, acc[rt][1], 0, 0, 0);
    }
  }
#pragma unroll
  for (int rt = 0; rt < 4; ++rt)
#pragma unroll
    for (int ct = 0; ct < 2; ++ct) {
      const int col = ((nt0 + ct) << 4) + lo;
      const float bv = ct ? bv1 : bv0;
#pragma unroll
      for (int rr = 0; rr < 4; ++rr) {
        const int orow = (rt << 4) + (hi << 2) + rr;
        float v = acc[rt][ct][rr] + bv;
        if (LEAKY) v = (v >= 0.f) ? v : 0.01f * v;
        *(short*)((char*)lds + swzaddr(outBase, 512, orow, col << 1)) = f2bf(v);
      }
    }
}

__launch_bounds__(512, 1)
__global__ void geo2vec_kernel(const float* __restrict__ xy, const int* __restrict__ idx,
    const float* __restrict__ emb,
    const float* __restrict__ b1a, const float* __restrict__ b1b,
    const float* __restrict__ ba, const float* __restrict__ bb,
    const float* __restrict__ W2, const float* __restrict__ b2,
    const short* __restrict__ wp, float* __restrict__ out)
{
  __shared__ short lds[53248];  // 104 KB
  const int tid = threadIdx.x;

  // ---- prologue: pos-encode + gather z -> xyz tile (64 x 320 bf16) ----
  {
    const int g = tid >> 3, j = tid & 7;  // 8 threads per row
    const int row = blockIdx.x * 64 + g;
    const float xv = xy[2 * row], yv = xy[2 * row + 1];
    const float rv = sqrtf(xv * xv + yv * yv);
    union { short s[8]; i32x4 v; } tmp;
#pragma unroll
    for (int i = 0; i < 8; ++i) {
      const int c = 8 * j + i;
      float fv;
      if (c < 2)       fv = c ? yv : xv;
      else if (c < 22) { int m = c - 2;  float f = 1.0f + (5.0f / 9.0f) * (m >> 1); fv = sinf(((m & 1) ? yv : xv) * f); }
      else if (c < 42) { int m = c - 22; float f = 1.0f + (5.0f / 9.0f) * (m >> 1); fv = cosf(((m & 1) ? yv : xv) * f); }
      else if (c < 44) fv = (c == 42) ? xv : yv;
      else if (c < 54) fv = sinf(rv * (1.0f + (5.0f / 9.0f) * (c - 44)));
      else             fv = cosf(rv * (1.0f + (5.0f / 9.0f) * (c - 54)));
      tmp.s[i] = f2bf(fv);
    }
    *(i32x4*)((char*)lds + swzaddr(0, 640, g, j << 4)) = tmp.v;
    const float* zr = emb + (size_t)(unsigned)idx[row] * 256;
#pragma unroll
    for (int c4 = 0; c4 < 4; ++c4) {
      const int cel = j * 32 + c4 * 8;  // z element 0..255
      const float4 f0 = *(const float4*)(zr + cel);
      const float4 f1 = *(const float4*)(zr + cel + 4);
      union { short s[8]; i32x4 v; } t2;
      t2.s[0] = f2bf(f0.x); t2.s[1] = f2bf(f0.y); t2.s[2] = f2bf(f0.z); t2.s[3] = f2bf(f0.w);
      t2.s[4] = f2bf(f1.x); t2.s[5] = f2bf(f1.y); t2.s[6] = f2bf(f1.z); t2.s[7] = f2bf(f1.w);
      *(i32x4*)((char*)lds + swzaddr(0, 640, g, (64 + cel) << 1)) = t2.v;
    }
  }
  __syncthreads();

  const int wave = tid >> 6, lane = tid & 63;
  // layer 1: t = leaky(xyz @ W1a + b1a) ; x = t @ W1b + b1b
  do_gemm<10, 10, true >(lds, 0, 640, 0, 640, wp, b1a, 73728, wave, lane);
  __syncthreads();
  do_gemm<8, 8, false>(lds, 73728, 512, 73728, 512, wp + 81920, b1b, 40960, wave, lane);
  __syncthreads();
  // 8 mid layers: t = leaky([xyz|x] @ Wa + ba) ; x = t @ Wb + bb
  for (int l = 0; l < 8; ++l) {
    do_gemm<18, 10, true >(lds, 0, 640, 40960, 512, wp + 147456 + l * 147456, ba + l * 256, 73728, wave, lane);
    __syncthreads();
    do_gemm<8, 8, false>(lds, 73728, 512, 73728, 512, wp + 1327104 + l * 65536, bb + l * 256, 40960, wave, lane);
    __syncthreads();
  }
  // final: out = x @ W2 + b2
  if (tid < 64) {
    float s = 0.f;
#pragma unroll
    for (int c = 0; c < 32; ++c) {
      const short* v = (const short*)((const char*)lds + swzaddr(40960, 512, tid, c << 4));
      const float4 w0 = *(const float4*)(W2 + (c << 3));
      const float4 w1 = *(const float4*)(W2 + (c << 3) + 4);
      s += bf2f(v[0]) * w0.x + bf2f(v[1]) * w0.y + bf2f(v[2]) * w0.z + bf2f(v[3]) * w0.w;
      s += bf2f(v[4]) * w1.x + bf2f(v[5]) * w1.y + bf2f(v[6]) * w1.z + bf2f(v[7]) * w1.w;
    }
    out[blockIdx.x * 64 + tid] = s + b2[0];
  }
}

extern "C" void kernel_launch(void* const* d_in, const int* in_sizes, int n_in,
                              void* d_out, int out_size, void* d_ws, size_t ws_size,
                              hipStream_t stream) {
  const float* xy  = (const float*)d_in[0];
  const int*   idx = (const int*)d_in[1];
  const float* emb = (const float*)d_in[2];
  const float* W1a = (const float*)d_in[3];
  const float* b1a = (const float*)d_in[4];
  const float* W1b = (const float*)d_in[5];
  const float* b1b = (const float*)d_in[6];
  const float* Wa  = (const float*)d_in[7];
  const float* ba  = (const float*)d_in[8];
  const float* Wb  = (const float*)d_in[9];
  const float* bb  = (const float*)d_in[10];
  const float* W2  = (const float*)d_in[11];
  const float* b2  = (const float*)d_in[12];
  short* ws = (short*)d_ws;  // 3,702,784 B of packed bf16 weights
  const int B = in_sizes[1];

  hipLaunchKernelGGL(pack_weights_kernel, dim3(904), dim3(256), 0, stream,
                     W1a, W1b, Wa, Wb, ws);
  hipLaunchKernelGGL(geo2vec_kernel, dim3(B / 64), dim3(512), 0, stream,
                     xy, idx, emb, b1a, b1b, ba, bb, W2, b2, ws, (float*)d_out);
}

// Round 4
// 796.568 us; speedup vs baseline: 1.0167x; 1.0160x over previous
//
#include <hip/hip_runtime.h>
#include <hip/hip_bf16.h>

// Geo2Vec fused MLP, bf16 MFMA. Round 4:
//  - waves split 2(rows) x 4(cols): halves A-frag LDS traffic
//  - swizzle ^((row&7)<<4)^((row&8)<<2): kills epilogue write bank conflicts
//  - depth-2 B register pipeline + cross-barrier prefetch with raw
//    lgkmcnt(0)+s_barrier (no vmcnt drain at barriers)

typedef __attribute__((ext_vector_type(8))) __bf16 bfv8;
typedef __attribute__((ext_vector_type(4))) float f32x4;
typedef __attribute__((ext_vector_type(4))) int i32x4;

__device__ __forceinline__ short f2bf(float f) {
  unsigned u = __builtin_bit_cast(unsigned, f);
  u = (u + 0x7fffu + ((u >> 16) & 1u)) >> 16;
  return (short)u;
}
__device__ __forceinline__ float bf2f(short s) {
  unsigned u = ((unsigned)(unsigned short)s) << 16;
  return __builtin_bit_cast(float, u);
}
// Swizzle: conflict-free for both 16-row A-reads and 4-row-group epilogue writes.
__device__ __forceinline__ int swzaddr(int base, int stride, int row, int colbyte) {
  return base + row * stride + (colbyte ^ (((row & 7) << 4) ^ ((row & 8) << 2)));
}
// LDS-visibility barrier that does NOT drain vmcnt (keeps B prefetch in flight).
__device__ __forceinline__ void ldsbar() {
  __builtin_amdgcn_sched_barrier(0);
  asm volatile("s_waitcnt lgkmcnt(0)");
  __builtin_amdgcn_s_barrier();
  __builtin_amdgcn_sched_barrier(0);
}

// ---------------- weight pack: fp32 row-major (K,256) -> bf16 B-frag-major ----
// packet p = (kt*16 + nt)*64 + lane ; dst[p*8+i] = W[kt*32 + 8*(lane>>4) + i][nt*16 + (lane&15)]
__global__ void pack_weights_kernel(const float* __restrict__ W1a, const float* __restrict__ W1b,
                                    const float* __restrict__ Wa, const float* __restrict__ Wb,
                                    short* __restrict__ ws) {
  int p = blockIdx.x * blockDim.x + threadIdx.x;
  const int P1 = 10240;           // W1a: 10 kt * 16 nt * 64
  const int P2 = P1 + 8192;       // W1b
  const int P3 = P2 + 8 * 18432;  // Wa
  const int P4 = P3 + 8 * 8192;   // Wb
  if (p >= P4) return;
  const float* src;
  int q;
  if (p < P1)      { src = W1a; q = p; }
  else if (p < P2) { src = W1b; q = p - P1; }
  else if (p < P3) { q = p - P2; int l = q / 18432; q -= l * 18432; src = Wa + l * 147456; }
  else             { q = p - P3; int l = q / 8192;  q -= l * 8192;  src = Wb + l * 65536; }
  const int lane = q & 63, t = q >> 6, nt = t & 15, kt = t >> 4;
  const int k0 = kt * 32 + ((lane >> 4) << 3);
  const int n  = (nt << 4) + (lane & 15);
  short* dst = ws + (size_t)p * 8;
#pragma unroll
  for (int i = 0; i < 8; ++i) dst[i] = f2bf(src[(size_t)(k0 + i) * 256 + n]);
}

// ---------------- fused MLP ----------------
// LDS (bytes): xyz [0,40960) stride 640 ; x [40960,73728) stride 512 ; t [73728,106496) stride 512
struct BPre { bfv8 b[4]; };

__device__ __forceinline__ BPre load_bpre(const short* __restrict__ wp, int wc, int lane) {
  BPre p;
#pragma unroll
  for (int ct = 0; ct < 4; ++ct)
    p.b[ct] = *(const bfv8*)(wp + ((((wc << 2) + ct) * 64 + lane) << 3));
  return p;
}

template<int NKT, int SPLITKT, bool LEAKY, bool PRE>
__device__ __forceinline__ BPre do_gemm(short* lds,
    int a1Base, int a1S, int a2Base, int a2S,
    const short* __restrict__ wp, const short* __restrict__ wpn,
    const float* __restrict__ bias, int outBase,
    int wr, int wc, int lane, BPre pre)
{
  const int lo = lane & 15, hi = lane >> 4;
  const int ntb = wc << 2;
  float bv[4];
#pragma unroll
  for (int ct = 0; ct < 4; ++ct) bv[ct] = bias[((ntb + ct) << 4) + lo];
  f32x4 acc[2][4];
#pragma unroll
  for (int r = 0; r < 2; ++r)
#pragma unroll
    for (int c = 0; c < 4; ++c) acc[r][c] = (f32x4)0.f;

  // 3-stage B rotation: st[kt%3] consumed at iter kt; loads issued 2 iters early.
  bfv8 st[3][4];
  BPre nxt = pre;
#pragma unroll
  for (int c = 0; c < 4; ++c) st[0][c] = pre.b[c];
  if (NKT > 1) {
#pragma unroll
    for (int c = 0; c < 4; ++c)
      st[1][c] = *(const bfv8*)(wp + (size_t)8192 + (((ntb + c) * 64 + lane) << 3));
  }
#pragma unroll
  for (int kt = 0; kt < NKT; ++kt) {
    if (kt + 2 < NKT) {
#pragma unroll
      for (int c = 0; c < 4; ++c)
        st[(kt + 2) % 3][c] = *(const bfv8*)(wp + (size_t)(kt + 2) * 8192 + (((ntb + c) * 64 + lane) << 3));
    } else if (PRE && (kt + 2 == NKT)) {
#pragma unroll
      for (int c = 0; c < 4; ++c)
        nxt.b[c] = *(const bfv8*)(wpn + (((ntb + c) * 64 + lane) << 3));
    }
    const int base  = (kt < SPLITKT) ? a1Base : a2Base;
    const int strd  = (kt < SPLITKT) ? a1S : a2S;
    const int kk    = (kt < SPLITKT) ? kt : kt - SPLITKT;
    const int kbyte = kk * 64 + (hi << 4);
#pragma unroll
    for (int rt = 0; rt < 2; ++rt) {
      const bfv8 a = *(const bfv8*)((const char*)lds + swzaddr(base, strd, (wr << 5) + (rt << 4) + lo, kbyte));
#pragma unroll
      for (int ct = 0; ct < 4; ++ct)
        acc[rt][ct] = __builtin_amdgcn_mfma_f32_16x16x32_bf16(a, st[kt % 3][ct], acc[rt][ct], 0, 0, 0);
    }
  }
  // epilogue: bias + (leaky) + bf16 round -> LDS (conflict-free swizzle)
#pragma unroll
  for (int rt = 0; rt < 2; ++rt)
#pragma unroll
    for (int ct = 0; ct < 4; ++ct)
#pragma unroll
      for (int rr = 0; rr < 4; ++rr) {
        const int orow = (wr << 5) + (rt << 4) + (hi << 2) + rr;
        const int col  = ((ntb + ct) << 4) + lo;
        float v = acc[rt][ct][rr] + bv[ct];
        if (LEAKY) v = (v >= 0.f) ? v : 0.01f * v;
        *(short*)((char*)lds + swzaddr(outBase, 512, orow, col << 1)) = f2bf(v);
      }
  return nxt;
}

__launch_bounds__(512, 1)
__global__ void geo2vec_kernel(const float* __restrict__ xy, const int* __restrict__ idx,
    const float* __restrict__ emb,
    const float* __restrict__ b1a, const float* __restrict__ b1b,
    const float* __restrict__ ba, const float* __restrict__ bb,
    const float* __restrict__ W2, const float* __restrict__ b2,
    const short* __restrict__ wp, float* __restrict__ out)
{
  __shared__ short lds[53248];  // 104 KB
  const int tid = threadIdx.x;
  const int wave = tid >> 6, lane = tid & 63;
  const int wr = wave >> 2, wc = wave & 3;

  // issue first gemm's B stage-0 loads immediately: hide under prologue trig
  BPre pre = load_bpre(wp, wc, lane);

  // ---- prologue: pos-encode + gather z -> xyz tile (64 x 320 bf16) ----
  {
    const int g = tid >> 3, j = tid & 7;  // 8 threads per row
    const int row = blockIdx.x * 64 + g;
    const float xv = xy[2 * row], yv = xy[2 * row + 1];
    const float rv = sqrtf(xv * xv + yv * yv);
    union { short s[8]; i32x4 v; } tmp;
#pragma unroll
    for (int i = 0; i < 8; ++i) {
      const int c = 8 * j + i;
      float fv;
      if (c < 2)       fv = c ? yv : xv;
      else if (c < 22) { int m = c - 2;  float f = 1.0f + (5.0f / 9.0f) * (m >> 1); fv = sinf(((m & 1) ? yv : xv) * f); }
      else if (c < 42) { int m = c - 22; float f = 1.0f + (5.0f / 9.0f) * (m >> 1); fv = cosf(((m & 1) ? yv : xv) * f); }
      else if (c < 44) fv = (c == 42) ? xv : yv;
      else if (c < 54) fv = sinf(rv * (1.0f + (5.0f / 9.0f) * (c - 44)));
      else             fv = cosf(rv * (1.0f + (5.0f / 9.0f) * (c - 54)));
      tmp.s[i] = f2bf(fv);
    }
    *(i32x4*)((char*)lds + swzaddr(0, 640, g, j << 4)) = tmp.v;
    const float* zr = emb + (size_t)(unsigned)idx[row] * 256;
#pragma unroll
    for (int c4 = 0; c4 < 4; ++c4) {
      const int cel = j * 32 + c4 * 8;
      const float4 f0 = *(const float4*)(zr + cel);
      const float4 f1 = *(const float4*)(zr + cel + 4);
      union { short s[8]; i32x4 v; } t2;
      t2.s[0] = f2bf(f0.x); t2.s[1] = f2bf(f0.y); t2.s[2] = f2bf(f0.z); t2.s[3] = f2bf(f0.w);
      t2.s[4] = f2bf(f1.x); t2.s[5] = f2bf(f1.y); t2.s[6] = f2bf(f1.z); t2.s[7] = f2bf(f1.w);
      *(i32x4*)((char*)lds + swzaddr(0, 640, g, (64 + cel) << 1)) = t2.v;
    }
  }
  ldsbar();

  // layer 1
  pre = do_gemm<10, 10, true,  true>(lds, 0, 640, 0, 640,       wp,          wp + 81920,  b1a, 73728, wr, wc, lane, pre);
  ldsbar();
  pre = do_gemm<8,  8,  false, true>(lds, 73728, 512, 73728, 512, wp + 81920, wp + 147456, b1b, 40960, wr, wc, lane, pre);
  ldsbar();
  // 8 mid layers
  for (int l = 0; l < 8; ++l) {
    const short* wa = wp + 147456 + l * 147456;
    const short* wb = wp + 1327104 + l * 65536;
    const short* wa_next = (l < 7) ? (wa + 147456) : wp;  // dummy (valid mem) on last layer
    pre = do_gemm<18, 10, true,  true>(lds, 0, 640, 40960, 512, wa, wb,      ba + l * 256, 73728, wr, wc, lane, pre);
    ldsbar();
    pre = do_gemm<8,  8,  false, true>(lds, 73728, 512, 73728, 512, wb, wa_next, bb + l * 256, 40960, wr, wc, lane, pre);
    ldsbar();
  }
  // final: out = x @ W2 + b2
  if (tid < 64) {
    float s = 0.f;
#pragma unroll
    for (int c = 0; c < 32; ++c) {
      const short* v = (const short*)((const char*)lds + swzaddr(40960, 512, tid, c << 4));
      const float4 w0 = *(const float4*)(W2 + (c << 3));
      const float4 w1 = *(const float4*)(W2 + (c << 3) + 4);
      s += bf2f(v[0]) * w0.x + bf2f(v[1]) * w0.y + bf2f(v[2]) * w0.z + bf2f(v[3]) * w0.w;
      s += bf2f(v[4]) * w1.x + bf2f(v[5]) * w1.y + bf2f(v[6]) * w1.z + bf2f(v[7]) * w1.w;
    }
    out[blockIdx.x * 64 + tid] = s + b2[0];
  }
}

extern "C" void kernel_launch(void* const* d_in, const int* in_sizes, int n_in,
                              void* d_out, int out_size, void* d_ws, size_t ws_size,
                              hipStream_t stream) {
  const float* xy  = (const float*)d_in[0];
  const int*   idx = (const int*)d_in[1];
  const float* emb = (const float*)d_in[2];
  const float* W1a = (const float*)d_in[3];
  const float* b1a = (const float*)d_in[4];
  const float* W1b = (const float*)d_in[5];
  const float* b1b = (const float*)d_in[6];
  const float* Wa  = (const float*)d_in[7];
  const float* ba  = (const float*)d_in[8];
  const float* Wb  = (const float*)d_in[9];
  const float* bb  = (const float*)d_in[10];
  const float* W2  = (const float*)d_in[11];
  const float* b2  = (const float*)d_in[12];
  short* ws = (short*)d_ws;
  const int B = in_sizes[1];

  hipLaunchKernelGGL(pack_weights_kernel, dim3(904), dim3(256), 0, stream,
                     W1a, W1b, Wa, Wb, ws);
  hipLaunchKernelGGL(geo2vec_kernel, dim3(B / 64), dim3(512), 0, stream,
                     xy, idx, emb, b1a, b1b, ba, bb, W2, b2, ws, (float*)d_out);
}

// Round 5
// 660.654 us; speedup vs baseline: 1.2259x; 1.2057x over previous
//
#include <hip/hip_runtime.h>
#include <hip/hip_bf16.h>

// Geo2Vec fused MLP, bf16 MFMA. Round 5: 16 waves (1024 thr) per 64-row block
// -> 4 waves/SIMD so B-L2 latency, LDS A-reads, and MFMA issue overlap across
// waves. Wave grid 2(rows)x8(cols), wave tile 32x32 (rt=2,ct=2).

typedef __attribute__((ext_vector_type(8))) __bf16 bfv8;
typedef __attribute__((ext_vector_type(8))) short s16x8;
typedef __attribute__((ext_vector_type(4))) float f32x4;
typedef __attribute__((ext_vector_type(4))) int i32x4;
typedef __attribute__((ext_vector_type(2))) int i32x2;

__device__ __forceinline__ short f2bf(float f) {
  unsigned u = __builtin_bit_cast(unsigned, f);
  u = (u + 0x7fffu + ((u >> 16) & 1u)) >> 16;
  return (short)u;
}
__device__ __forceinline__ float bf2f(short s) {
  unsigned u = ((unsigned)(unsigned short)s) << 16;
  return __builtin_bit_cast(float, u);
}
// Swizzle: conflict-free for 16-row A-reads and 4-row-group epilogue writes.
__device__ __forceinline__ int swzaddr(int base, int stride, int row, int colbyte) {
  return base + row * stride + (colbyte ^ (((row & 7) << 4) ^ ((row & 8) << 2)));
}
// LDS-visibility barrier that does NOT drain vmcnt (keeps B prefetch in flight).
__device__ __forceinline__ void ldsbar() {
  __builtin_amdgcn_sched_barrier(0);
  asm volatile("s_waitcnt lgkmcnt(0)");
  __builtin_amdgcn_s_barrier();
  __builtin_amdgcn_sched_barrier(0);
}

// ---------------- weight pack: fp32 row-major (K,256) -> bf16 B-frag-major ----
// packet p = (kt*16 + nt)*64 + lane ; dst[p*8+i] = W[kt*32 + 8*(lane>>4) + i][nt*16 + (lane&15)]
__global__ void pack_weights_kernel(const float* __restrict__ W1a, const float* __restrict__ W1b,
                                    const float* __restrict__ Wa, const float* __restrict__ Wb,
                                    short* __restrict__ ws) {
  int p = blockIdx.x * blockDim.x + threadIdx.x;
  const int P1 = 10240;           // W1a: 10 kt * 16 nt * 64
  const int P2 = P1 + 8192;       // W1b
  const int P3 = P2 + 8 * 18432;  // Wa
  const int P4 = P3 + 8 * 8192;   // Wb
  if (p >= P4) return;
  const float* src;
  int q;
  if (p < P1)      { src = W1a; q = p; }
  else if (p < P2) { src = W1b; q = p - P1; }
  else if (p < P3) { q = p - P2; int l = q / 18432; q -= l * 18432; src = Wa + l * 147456; }
  else             { q = p - P3; int l = q / 8192;  q -= l * 8192;  src = Wb + l * 65536; }
  const int lane = q & 63, t = q >> 6, nt = t & 15, kt = t >> 4;
  const int k0 = kt * 32 + ((lane >> 4) << 3);
  const int n  = (nt << 4) + (lane & 15);
  short* dst = ws + (size_t)p * 8;
#pragma unroll
  for (int i = 0; i < 8; ++i) dst[i] = f2bf(src[(size_t)(k0 + i) * 256 + n]);
}

// ---------------- fused MLP ----------------
// LDS (bytes): xyz [0,40960) stride 640 ; x [40960,73728) stride 512 ; t [73728,106496) stride 512
struct BPre { bfv8 b[2]; };

__device__ __forceinline__ bfv8 bfrag(const short* __restrict__ wp, int kt, int nt, int lane) {
  return *(const bfv8*)(wp + (((size_t)(kt * 16 + nt) * 64 + lane) << 3));
}
__device__ __forceinline__ BPre load_bpre(const short* __restrict__ wp, int wc, int lane) {
  BPre p;
  p.b[0] = bfrag(wp, 0, (wc << 1), lane);
  p.b[1] = bfrag(wp, 0, (wc << 1) + 1, lane);
  return p;
}

template<int NKT, int SPLITKT, bool LEAKY, bool PRE>
__device__ __forceinline__ BPre do_gemm(short* lds,
    int a1Base, int a1S, int a2Base, int a2S,
    const short* __restrict__ wp, const short* __restrict__ wpn,
    const float* __restrict__ bias, int outBase,
    int wr, int wc, int lane, BPre pre)
{
  const int lo = lane & 15, hi = lane >> 4;
  const int ntb = wc << 1;   // 2 coltiles per wave
  const int wrb = wr << 5;   // 32 rows per wave
  float bv[2];
#pragma unroll
  for (int ct = 0; ct < 2; ++ct) bv[ct] = bias[((ntb + ct) << 4) + lo];
  f32x4 acc[2][2];
#pragma unroll
  for (int r = 0; r < 2; ++r)
#pragma unroll
    for (int c = 0; c < 2; ++c) acc[r][c] = (f32x4)0.f;

  // 3-stage B register rotation: st[kt%3] consumed at kt; loads 2 iters early.
  bfv8 st[3][2];
  BPre nxt = pre;
  st[0][0] = pre.b[0]; st[0][1] = pre.b[1];
  if (NKT > 1) {
    st[1][0] = bfrag(wp, 1, ntb, lane);
    st[1][1] = bfrag(wp, 1, ntb + 1, lane);
  }
#pragma unroll
  for (int kt = 0; kt < NKT; ++kt) {
    if (kt + 2 < NKT) {
      st[(kt + 2) % 3][0] = bfrag(wp, kt + 2, ntb, lane);
      st[(kt + 2) % 3][1] = bfrag(wp, kt + 2, ntb + 1, lane);
    } else if (PRE && (kt + 2 == NKT)) {
      nxt.b[0] = bfrag(wpn, 0, ntb, lane);
      nxt.b[1] = bfrag(wpn, 0, ntb + 1, lane);
    }
    const int base  = (kt < SPLITKT) ? a1Base : a2Base;
    const int strd  = (kt < SPLITKT) ? a1S : a2S;
    const int kk    = (kt < SPLITKT) ? kt : kt - SPLITKT;
    const int kbyte = kk * 64 + (hi << 4);
#pragma unroll
    for (int rt = 0; rt < 2; ++rt) {
      const bfv8 a = *(const bfv8*)((const char*)lds + swzaddr(base, strd, wrb + (rt << 4) + lo, kbyte));
#pragma unroll
      for (int ct = 0; ct < 2; ++ct)
        acc[rt][ct] = __builtin_amdgcn_mfma_f32_16x16x32_bf16(a, st[kt % 3][ct], acc[rt][ct], 0, 0, 0);
    }
  }
  // epilogue: bias + (leaky) + bf16 round -> LDS
#pragma unroll
  for (int rt = 0; rt < 2; ++rt)
#pragma unroll
    for (int ct = 0; ct < 2; ++ct)
#pragma unroll
      for (int rr = 0; rr < 4; ++rr) {
        const int orow = wrb + (rt << 4) + (hi << 2) + rr;
        const int col  = ((ntb + ct) << 4) + lo;
        float v = acc[rt][ct][rr] + bv[ct];
        if (LEAKY) v = (v >= 0.f) ? v : 0.01f * v;
        *(short*)((char*)lds + swzaddr(outBase, 512, orow, col << 1)) = f2bf(v);
      }
  return nxt;
}

__launch_bounds__(1024, 1)
__global__ void geo2vec_kernel(const float* __restrict__ xy, const int* __restrict__ idx,
    const float* __restrict__ emb,
    const float* __restrict__ b1a, const float* __restrict__ b1b,
    const float* __restrict__ ba, const float* __restrict__ bb,
    const float* __restrict__ W2, const float* __restrict__ b2,
    const short* __restrict__ wp, float* __restrict__ out)
{
  __shared__ short lds[53248];  // 104 KB
  const int tid = threadIdx.x;
  const int wave = tid >> 6, lane = tid & 63;
  const int wr = wave >> 3, wc = wave & 7;

  // issue first gemm's B stage-0 loads immediately: hide under prologue trig
  BPre pre = load_bpre(wp, wc, lane);

  // ---- prologue: pos-encode + gather z -> xyz tile (64 x 320 bf16) ----
  {
    const int g = tid >> 4, j = tid & 15;  // 16 threads per row
    const int row = blockIdx.x * 64 + g;
    const float xv = xy[2 * row], yv = xy[2 * row + 1];
    const float rv = sqrtf(xv * xv + yv * yv);
    // pe cols 4j..4j+3 (8B store; swizzle moves 16B units so 8B stays intact)
    union { short s[4]; i32x2 v; } tmp;
#pragma unroll
    for (int i = 0; i < 4; ++i) {
      const int c = 4 * j + i;
      float fv;
      if (c < 2)       fv = c ? yv : xv;
      else if (c < 22) { int m = c - 2;  float f = 1.0f + (5.0f / 9.0f) * (m >> 1); fv = sinf(((m & 1) ? yv : xv) * f); }
      else if (c < 42) { int m = c - 22; float f = 1.0f + (5.0f / 9.0f) * (m >> 1); fv = cosf(((m & 1) ? yv : xv) * f); }
      else if (c < 44) fv = (c == 42) ? xv : yv;
      else if (c < 54) fv = sinf(rv * (1.0f + (5.0f / 9.0f) * (c - 44)));
      else             fv = cosf(rv * (1.0f + (5.0f / 9.0f) * (c - 54)));
      tmp.s[i] = f2bf(fv);
    }
    *(i32x2*)((char*)lds + swzaddr(0, 640, g, j << 3)) = tmp.v;
    // z cols 16j..16j+15
    const float* zr = emb + (size_t)(unsigned)idx[row] * 256;
#pragma unroll
    for (int c8 = 0; c8 < 2; ++c8) {
      const int cel = j * 16 + c8 * 8;
      const float4 f0 = *(const float4*)(zr + cel);
      const float4 f1 = *(const float4*)(zr + cel + 4);
      union { short s[8]; i32x4 v; } t2;
      t2.s[0] = f2bf(f0.x); t2.s[1] = f2bf(f0.y); t2.s[2] = f2bf(f0.z); t2.s[3] = f2bf(f0.w);
      t2.s[4] = f2bf(f1.x); t2.s[5] = f2bf(f1.y); t2.s[6] = f2bf(f1.z); t2.s[7] = f2bf(f1.w);
      *(i32x4*)((char*)lds + swzaddr(0, 640, g, (64 + cel) << 1)) = t2.v;
    }
  }
  ldsbar();

  // layer 1
  pre = do_gemm<10, 10, true,  true>(lds, 0, 640, 0, 640,        wp,          wp + 81920,  b1a, 73728, wr, wc, lane, pre);
  ldsbar();
  pre = do_gemm<8,  8,  false, true>(lds, 73728, 512, 73728, 512, wp + 81920, wp + 147456, b1b, 40960, wr, wc, lane, pre);
  ldsbar();
  // 8 mid layers
  for (int l = 0; l < 8; ++l) {
    const short* wa = wp + 147456 + l * 147456;
    const short* wb = wp + 1327104 + l * 65536;
    const short* wa_next = (l < 7) ? (wa + 147456) : wp;  // dummy (valid mem) on last layer
    pre = do_gemm<18, 10, true,  true>(lds, 0, 640, 40960, 512,   wa, wb,      ba + l * 256, 73728, wr, wc, lane, pre);
    ldsbar();
    pre = do_gemm<8,  8,  false, true>(lds, 73728, 512, 73728, 512, wb, wa_next, bb + l * 256, 40960, wr, wc, lane, pre);
    ldsbar();
  }
  // final: out = x @ W2 + b2 ; 16 threads per row, width-16 shuffle reduce
  {
    const int r = tid >> 4, j = tid & 15;
    float s = 0.f;
#pragma unroll
    for (int h = 0; h < 2; ++h) {
      const int cb = 32 * j + 16 * h;                 // colbyte of 8 cols
      const s16x8 v = *(const s16x8*)((const char*)lds + swzaddr(40960, 512, r, cb));
      const int c0 = 16 * j + 8 * h;
      const float4 w0 = *(const float4*)(W2 + c0);
      const float4 w1 = *(const float4*)(W2 + c0 + 4);
      s += bf2f(v[0]) * w0.x + bf2f(v[1]) * w0.y + bf2f(v[2]) * w0.z + bf2f(v[3]) * w0.w;
      s += bf2f(v[4]) * w1.x + bf2f(v[5]) * w1.y + bf2f(v[6]) * w1.z + bf2f(v[7]) * w1.w;
    }
    s += __shfl_xor(s, 1); s += __shfl_xor(s, 2);
    s += __shfl_xor(s, 4); s += __shfl_xor(s, 8);
    if (j == 0) out[blockIdx.x * 64 + r] = s + b2[0];
  }
}

extern "C" void kernel_launch(void* const* d_in, const int* in_sizes, int n_in,
                              void* d_out, int out_size, void* d_ws, size_t ws_size,
                              hipStream_t stream) {
  const float* xy  = (const float*)d_in[0];
  const int*   idx = (const int*)d_in[1];
  const float* emb = (const float*)d_in[2];
  const float* W1a = (const float*)d_in[3];
  const float* b1a = (const float*)d_in[4];
  const float* W1b = (const float*)d_in[5];
  const float* b1b = (const float*)d_in[6];
  const float* Wa  = (const float*)d_in[7];
  const float* ba  = (const float*)d_in[8];
  const float* Wb  = (const float*)d_in[9];
  const float* bb  = (const float*)d_in[10];
  const float* W2  = (const float*)d_in[11];
  const float* b2  = (const float*)d_in[12];
  short* ws = (short*)d_ws;
  const int B = in_sizes[1];

  hipLaunchKernelGGL(pack_weights_kernel, dim3(904), dim3(256), 0, stream,
                     W1a, W1b, Wa, Wb, ws);
  hipLaunchKernelGGL(geo2vec_kernel, dim3(B / 64), dim3(1024), 0, stream,
                     xy, idx, emb, b1a, b1b, ba, bb, W2, b2, ws, (float*)d_out);
}

// Round 6
// 614.024 us; speedup vs baseline: 1.3190x; 1.0759x over previous
//
#include <hip/hip_runtime.h>
#include <hip/hip_bf16.h>

// Geo2Vec fused MLP, bf16 MFMA. Round 6: split-K wave specialization.
// 16 waves = (s in {0,1}) x (wc in 0..7). Each wave: 64 rows x 32 cols over
// HALF the kt range -> B-frags loaded exactly once per block (B-L2 traffic
// halved). Partials combined through a dedicated 32KB f32 LDS stage region.

typedef __attribute__((ext_vector_type(8))) __bf16 bfv8;
typedef __attribute__((ext_vector_type(8))) short s16x8;
typedef __attribute__((ext_vector_type(4))) float f32x4;
typedef __attribute__((ext_vector_type(4))) int i32x4;
typedef __attribute__((ext_vector_type(2))) int i32x2;

__device__ __forceinline__ short f2bf(float f) {
  unsigned u = __builtin_bit_cast(unsigned, f);
  u = (u + 0x7fffu + ((u >> 16) & 1u)) >> 16;
  return (short)u;
}
__device__ __forceinline__ float bf2f(short s) {
  unsigned u = ((unsigned)(unsigned short)s) << 16;
  return __builtin_bit_cast(float, u);
}
// Swizzle: conflict-free for 16-row A-reads and 4-row-group epilogue writes.
__device__ __forceinline__ int swzaddr(int base, int stride, int row, int colbyte) {
  return base + row * stride + (colbyte ^ (((row & 7) << 4) ^ ((row & 8) << 2)));
}
// LDS-visibility barrier that does NOT drain vmcnt (keeps B prefetch in flight).
__device__ __forceinline__ void ldsbar() {
  __builtin_amdgcn_sched_barrier(0);
  asm volatile("s_waitcnt lgkmcnt(0)");
  __builtin_amdgcn_s_barrier();
  __builtin_amdgcn_sched_barrier(0);
}

// ---------------- weight pack: fp32 row-major (K,256) -> bf16 B-frag-major ----
// packet p = (kt*16 + nt)*64 + lane ; dst[p*8+i] = W[kt*32 + 8*(lane>>4) + i][nt*16 + (lane&15)]
__global__ void pack_weights_kernel(const float* __restrict__ W1a, const float* __restrict__ W1b,
                                    const float* __restrict__ Wa, const float* __restrict__ Wb,
                                    short* __restrict__ ws) {
  int p = blockIdx.x * blockDim.x + threadIdx.x;
  const int P1 = 10240;           // W1a: 10 kt * 16 nt * 64
  const int P2 = P1 + 8192;       // W1b
  const int P3 = P2 + 8 * 18432;  // Wa
  const int P4 = P3 + 8 * 8192;   // Wb
  if (p >= P4) return;
  const float* src;
  int q;
  if (p < P1)      { src = W1a; q = p; }
  else if (p < P2) { src = W1b; q = p - P1; }
  else if (p < P3) { q = p - P2; int l = q / 18432; q -= l * 18432; src = Wa + l * 147456; }
  else             { q = p - P3; int l = q / 8192;  q -= l * 8192;  src = Wb + l * 65536; }
  const int lane = q & 63, t = q >> 6, nt = t & 15, kt = t >> 4;
  const int k0 = kt * 32 + ((lane >> 4) << 3);
  const int n  = (nt << 4) + (lane & 15);
  short* dst = ws + (size_t)p * 8;
#pragma unroll
  for (int i = 0; i < 8; ++i) dst[i] = f2bf(src[(size_t)(k0 + i) * 256 + n]);
}

// ---------------- fused MLP ----------------
// LDS (bytes): xyz [0,40960) stride 640 ; x [40960,73728) stride 512 ;
//              t [73728,106496) stride 512 ; f32 stage [106496,139264)
#define STG_BASE 106496

struct BPre { bfv8 b[2]; };

__device__ __forceinline__ bfv8 bfrag(const short* __restrict__ wp, int kt, int nt, int lane) {
  return *(const bfv8*)(wp + (((size_t)(kt * 16 + nt) * 64 + lane) << 3));
}

// Compute half of a GEMM's kt range [KT0,KT1), acc over 64 rows x 32 cols.
template<int KT0, int KT1, int SPLITKT>
__device__ __forceinline__ void ghalf(const short* lds,
    int a1Base, int a1S, int a2Base, int a2S,
    const short* __restrict__ wp, int wc, int lane,
    f32x4 (&acc)[4][2], BPre pre)
{
  constexpr int H = KT1 - KT0;
  const int lo = lane & 15, hi = lane >> 4;
  const int ntb = wc << 1;
  bfv8 st[3][2];
  st[0][0] = pre.b[0]; st[0][1] = pre.b[1];
  if (H > 1) {
    st[1][0] = bfrag(wp, KT0 + 1, ntb, lane);
    st[1][1] = bfrag(wp, KT0 + 1, ntb + 1, lane);
  }
#pragma unroll
  for (int i = 0; i < H; ++i) {
    const int kt = KT0 + i;
    if (i + 2 < H) {
      st[(i + 2) % 3][0] = bfrag(wp, kt + 2, ntb, lane);
      st[(i + 2) % 3][1] = bfrag(wp, kt + 2, ntb + 1, lane);
    }
    const int base  = (kt < SPLITKT) ? a1Base : a2Base;
    const int strd  = (kt < SPLITKT) ? a1S : a2S;
    const int kk    = (kt < SPLITKT) ? kt : kt - SPLITKT;
    const int kbyte = kk * 64 + (hi << 4);
#pragma unroll
    for (int rt = 0; rt < 4; ++rt) {
      const bfv8 a = *(const bfv8*)((const char*)lds + swzaddr(base, strd, (rt << 4) + lo, kbyte));
      acc[rt][0] = __builtin_amdgcn_mfma_f32_16x16x32_bf16(a, st[i % 3][0], acc[rt][0], 0, 0, 0);
      acc[rt][1] = __builtin_amdgcn_mfma_f32_16x16x32_bf16(a, st[i % 3][1], acc[rt][1], 0, 0, 0);
    }
  }
}

template<int NKT, int SPLITKT, bool LEAKY>
__device__ __forceinline__ BPre do_gemm(short* lds,
    int a1Base, int a1S, int a2Base, int a2S,
    const short* __restrict__ wp, const short* __restrict__ wpn, int nxh,
    const float* __restrict__ bias, int outBase,
    int s, int wc, int lane, BPre pre)
{
  const int lo = lane & 15, hi = lane >> 4;
  f32x4 acc[4][2];
#pragma unroll
  for (int r = 0; r < 4; ++r) { acc[r][0] = (f32x4)0.f; acc[r][1] = (f32x4)0.f; }

  if (s == 0) ghalf<0, NKT / 2, SPLITKT>(lds, a1Base, a1S, a2Base, a2S, wp, wc, lane, acc, pre);
  else        ghalf<NKT / 2, NKT, SPLITKT>(lds, a1Base, a1S, a2Base, a2S, wp, wc, lane, acc, pre);

  // prefetch next gemm's first B frags for this wave's half (covered by epilogue)
  BPre nxt;
  nxt.b[0] = bfrag(wpn, s * nxh, (wc << 1), lane);
  nxt.b[1] = bfrag(wpn, s * nxh, (wc << 1) + 1, lane);

  const float bv0 = bias[(wc << 5) + lo];
  const float bv1 = bias[(wc << 5) + 16 + lo];
  char* stg = (char*)lds + STG_BASE;
  const int slot = ((wc << 6) + lane) << 4;  // per-(wc,lane) 16B granule, 4 planes of 8KB

#pragma unroll
  for (int p = 0; p < 2; ++p) {
    if (s) {  // dump partials: 4 x ds_write_b128, fully coalesced
      *(f32x4*)(stg + slot)         = acc[2 * p][0];
      *(f32x4*)(stg + 8192 + slot)  = acc[2 * p][1];
      *(f32x4*)(stg + 16384 + slot) = acc[2 * p + 1][0];
      *(f32x4*)(stg + 24576 + slot) = acc[2 * p + 1][1];
    }
    ldsbar();
    if (!s) {
      acc[2 * p][0]     += *(const f32x4*)(stg + slot);
      acc[2 * p][1]     += *(const f32x4*)(stg + 8192 + slot);
      acc[2 * p + 1][0] += *(const f32x4*)(stg + 16384 + slot);
      acc[2 * p + 1][1] += *(const f32x4*)(stg + 24576 + slot);
#pragma unroll
      for (int rq = 0; rq < 2; ++rq) {
        const int rt = 2 * p + rq;
#pragma unroll
        for (int ct = 0; ct < 2; ++ct)
#pragma unroll
          for (int rr = 0; rr < 4; ++rr) {
            const int orow = (rt << 4) + (hi << 2) + rr;
            const int col  = (wc << 5) + (ct << 4) + lo;
            float v = acc[rt][ct][rr] + (ct ? bv1 : bv0);
            if (LEAKY) v = (v >= 0.f) ? v : 0.01f * v;
            *(short*)((char*)lds + swzaddr(outBase, 512, orow, col << 1)) = f2bf(v);
          }
      }
    }
    ldsbar();  // protects stage-slot reuse (p=0) / out-region turnover (p=1)
  }
  return nxt;
}

__launch_bounds__(1024, 1)
__global__ void geo2vec_kernel(const float* __restrict__ xy, const int* __restrict__ idx,
    const float* __restrict__ emb,
    const float* __restrict__ b1a, const float* __restrict__ b1b,
    const float* __restrict__ ba, const float* __restrict__ bb,
    const float* __restrict__ W2, const float* __restrict__ b2,
    const short* __restrict__ wp, float* __restrict__ out)
{
  __shared__ short lds[69632];  // 136 KB
  const int tid = threadIdx.x;
  const int wave = tid >> 6, lane = tid & 63;
  const int s = wave >> 3, wc = wave & 7;

  // issue first gemm's B stage-0 loads immediately: hide under prologue trig
  BPre pre;
  pre.b[0] = bfrag(wp, s * 5, (wc << 1), lane);
  pre.b[1] = bfrag(wp, s * 5, (wc << 1) + 1, lane);

  // ---- prologue: pos-encode + gather z -> xyz tile (64 x 320 bf16) ----
  {
    const int g = tid >> 4, j = tid & 15;  // 16 threads per row
    const int row = blockIdx.x * 64 + g;
    const float xv = xy[2 * row], yv = xy[2 * row + 1];
    const float rv = sqrtf(xv * xv + yv * yv);
    union { short sh[4]; i32x2 v; } tmp;
#pragma unroll
    for (int i = 0; i < 4; ++i) {
      const int c = 4 * j + i;
      float fv;
      if (c < 2)       fv = c ? yv : xv;
      else if (c < 22) { int m = c - 2;  float f = 1.0f + (5.0f / 9.0f) * (m >> 1); fv = sinf(((m & 1) ? yv : xv) * f); }
      else if (c < 42) { int m = c - 22; float f = 1.0f + (5.0f / 9.0f) * (m >> 1); fv = cosf(((m & 1) ? yv : xv) * f); }
      else if (c < 44) fv = (c == 42) ? xv : yv;
      else if (c < 54) fv = sinf(rv * (1.0f + (5.0f / 9.0f) * (c - 44)));
      else             fv = cosf(rv * (1.0f + (5.0f / 9.0f) * (c - 54)));
      tmp.sh[i] = f2bf(fv);
    }
    *(i32x2*)((char*)lds + swzaddr(0, 640, g, j << 3)) = tmp.v;
    const float* zr = emb + (size_t)(unsigned)idx[row] * 256;
#pragma unroll
    for (int c8 = 0; c8 < 2; ++c8) {
      const int cel = j * 16 + c8 * 8;
      const float4 f0 = *(const float4*)(zr + cel);
      const float4 f1 = *(const float4*)(zr + cel + 4);
      union { short sh[8]; i32x4 v; } t2;
      t2.sh[0] = f2bf(f0.x); t2.sh[1] = f2bf(f0.y); t2.sh[2] = f2bf(f0.z); t2.sh[3] = f2bf(f0.w);
      t2.sh[4] = f2bf(f1.x); t2.sh[5] = f2bf(f1.y); t2.sh[6] = f2bf(f1.z); t2.sh[7] = f2bf(f1.w);
      *(i32x4*)((char*)lds + swzaddr(0, 640, g, (64 + cel) << 1)) = t2.v;
    }
  }
  ldsbar();

  // layer 1
  pre = do_gemm<10, 10, true >(lds, 0, 640, 0, 640,         wp,         wp + 81920,  4, b1a, 73728, s, wc, lane, pre);
  pre = do_gemm<8,  8,  false>(lds, 73728, 512, 73728, 512, wp + 81920, wp + 147456, 9, b1b, 40960, s, wc, lane, pre);
  // 8 mid layers
  for (int l = 0; l < 8; ++l) {
    const short* wa = wp + 147456 + l * 147456;
    const short* wb = wp + 1327104 + l * 65536;
    const short* wan = (l < 7) ? (wa + 147456) : wp;  // dummy (valid mem) on last layer
    pre = do_gemm<18, 10, true >(lds, 0, 640, 40960, 512,     wa, wb,  4, ba + l * 256, 73728, s, wc, lane, pre);
    pre = do_gemm<8,  8,  false>(lds, 73728, 512, 73728, 512, wb, wan, 9, bb + l * 256, 40960, s, wc, lane, pre);
  }
  // final: out = x @ W2 + b2 ; 16 threads per row, width-16 shuffle reduce
  {
    const int r = tid >> 4, j = tid & 15;
    float sum = 0.f;
#pragma unroll
    for (int h = 0; h < 2; ++h) {
      const int cb = 32 * j + 16 * h;
      const s16x8 v = *(const s16x8*)((const char*)lds + swzaddr(40960, 512, r, cb));
      const int c0 = 16 * j + 8 * h;
      const float4 w0 = *(const float4*)(W2 + c0);
      const float4 w1 = *(const float4*)(W2 + c0 + 4);
      sum += bf2f(v[0]) * w0.x + bf2f(v[1]) * w0.y + bf2f(v[2]) * w0.z + bf2f(v[3]) * w0.w;
      sum += bf2f(v[4]) * w1.x + bf2f(v[5]) * w1.y + bf2f(v[6]) * w1.z + bf2f(v[7]) * w1.w;
    }
    sum += __shfl_xor(sum, 1); sum += __shfl_xor(sum, 2);
    sum += __shfl_xor(sum, 4); sum += __shfl_xor(sum, 8);
    if (j == 0) out[blockIdx.x * 64 + r] = sum + b2[0];
  }
}

extern "C" void kernel_launch(void* const* d_in, const int* in_sizes, int n_in,
                              void* d_out, int out_size, void* d_ws, size_t ws_size,
                              hipStream_t stream) {
  const float* xy  = (const float*)d_in[0];
  const int*   idx = (const int*)d_in[1];
  const float* emb = (const float*)d_in[2];
  const float* W1a = (const float*)d_in[3];
  const float* b1a = (const float*)d_in[4];
  const float* W1b = (const float*)d_in[5];
  const float* b1b = (const float*)d_in[6];
  const float* Wa  = (const float*)d_in[7];
  const float* ba  = (const float*)d_in[8];
  const float* Wb  = (const float*)d_in[9];
  const float* bb  = (const float*)d_in[10];
  const float* W2  = (const float*)d_in[11];
  const float* b2  = (const float*)d_in[12];
  short* ws = (short*)d_ws;
  const int B = in_sizes[1];

  hipLaunchKernelGGL(pack_weights_kernel, dim3(904), dim3(256), 0, stream,
                     W1a, W1b, Wa, Wb, ws);
  hipLaunchKernelGGL(geo2vec_kernel, dim3(B / 64), dim3(1024), 0, stream,
                     xy, idx, emb, b1a, b1b, ba, bb, W2, b2, ws, (float*)d_out);
}